// Round 9
// baseline (40.697 us; speedup 1.0000x reference)
//
#include <hip/hip_runtime.h>
#include <hip/hip_bf16.h>
#include <math.h>

typedef __attribute__((ext_vector_type(8))) short short8;
typedef __attribute__((ext_vector_type(4))) float f32x4;
typedef __attribute__((ext_vector_type(16))) float f32x16;
typedef unsigned int u32;
typedef unsigned long long u64;

// fast round-to-nearest-even f32 -> bf16 (finite values)
__device__ __forceinline__ ushort f2bf(float f) {
    u32 u = __float_as_uint(f);
    return (ushort)((u + 0x7fffu + ((u >> 16) & 1u)) >> 16);
}

// ---------------------------------------------------------------------------
// Weight pack: layer_weight (32,144,3,3) f32 -> bf16 A-fragments for
// mfma_f32_32x32x16_bf16 (weights = A operand, M=32=oc, K=144).
// Page = tap*9 + ks. A-frag: row(oc) = lane&31, k = ks*16 + (lane>>5)*8 + e.
// ---------------------------------------------------------------------------
__global__ void wtrans(const float* __restrict__ lw, ushort* __restrict__ w2) {
    int t = blockIdx.x * 256 + threadIdx.x;
    if (t >= 5184) return;
    int l    = t & 63;
    int page = t >> 6;          // 0..80
    int ks  = page % 9;
    int tap = page / 9;
    int oc = l & 31;
    int kbase = ks * 16 + ((l >> 5) << 3);
    short8 v;
#pragma unroll
    for (int e = 0; e < 8; ++e) {
        int k = kbase + e;      // < 144 always
        v[e] = (short)f2bf(lw[(oc * 144 + k) * 9 + tap]);
    }
    ((short8*)w2)[t] = v;
}

// ---------------------------------------------------------------------------
// MFMA implicit-GEMM KAN conv, 32x32x16 bf16, K=144. Raw bf16 y out.
// Block = (b, g, 4x16 tile), halo 6x18, row stride 152 ushort (19x16B, odd).
// Waves own taps {0,1},{2,3},{4,5},{6,7,8}; each computes both pixel tiles.
// 6-slot stride-20 combine scratch (conflict-free, fits in Fs).
// ---------------------------------------------------------------------------
__global__ __launch_bounds__(256, 4) void kanconv(const float* __restrict__ x,
                                                  const ushort* __restrict__ w2,
                                                  ushort* __restrict__ yraw) {
    __shared__ __align__(16) ushort Fs[108 * 152];   // 32,832 B
    const int tid  = threadIdx.x;
    const int tile = blockIdx.x;          // 0..63 : 16 row-tiles x 4 col-tiles
    const int b    = blockIdx.y;
    const int g    = blockIdx.z;
    const int h0 = (tile >> 2) * 4;
    const int w0 = (tile & 3) * 16;
    const float* xg = x + ((size_t)(b * 64 + g * 16)) * 4096;

    // ---- phase 1: prefetch the 7 x values (independent loads) ----
    float xv[7];
    unsigned imgbits = 0;
#pragma unroll
    for (int it = 0; it < 7; ++it) {
        int e = it * 256 + tid;
        float v = 0.f;
        if (e < 1728) {
            int icg = e / 108;
            int p   = e - icg * 108;
            int py = p / 18, px = p - py * 18;
            int hy = h0 + py - 1, wx = w0 + px - 1;
            if (((unsigned)hy < 64u) && ((unsigned)wx < 64u)) {
                v = xg[icg * 4096 + hy * 64 + wx];
                imgbits |= (1u << it);
            }
        }
        xv[it] = v;
    }

    // ---- phase 2: feature math + LDS writes ----
#pragma unroll
    for (int it = 0; it < 7; ++it) {
        int e = it * 256 + tid;
        if (e < 1728) {
            int icg = e / 108;
            int p   = e - icg * 108;
            bool img = (imgbits >> it) & 1u;
            float v = xv[it];
            // uniform cubic B-spline closed form; knots -2.2 + 0.4*i
            float tpos = (v + 2.2f) * 2.5f;
            float cf = floorf(tpos);
            int ci = (int)cf;
            float u = tpos - cf;
            float u2 = u * u, u3 = u2 * u, om = 1.f - u;
            const float s6 = 1.f / 6.f;
            float q0 = om * om * om * s6;
            float q1 = (4.f - 6.f * u2 + 3.f * u3) * s6;
            float q2 = (1.f + 3.f * u + 3.f * u2 - 3.f * u3) * s6;
            float q3 = u3 * s6;
            u64 Q =   (u64)f2bf(q0)
                    | ((u64)f2bf(q1) << 16)
                    | ((u64)f2bf(q2) << 32)
                    | ((u64)f2bf(q3) << 48);
            u64 lo = 0, hi = 0;
            if (img && ci >= 0 && ci <= 10) {
                int s = ci * 16 - 48;
                if (s < 0)        { lo = Q >> (-s); }
                else if (s < 64)  { lo = Q << s; hi = s ? (Q >> (64 - s)) : 0ull; }
                else              { hi = Q << (s - 64); }
            }
            union { u64 u64v[2]; short8 s8; } un;
            un.u64v[0] = lo; un.u64v[1] = hi;
            ushort* row = &Fs[p * 152];
            *(short8*)(row + icg * 8) = un.s8;
            // gelu via branch-free poly erf (A&S 7.1.26); v==0 -> ge==0
            float z  = v * 0.70710678118654752f;
            float az = fabsf(z);
            float tt = 1.f / fmaf(0.3275911f, az, 1.f);
            float poly = tt * fmaf(tt, fmaf(tt, fmaf(tt, fmaf(tt, 1.061405429f,
                          -1.453152027f), 1.421413741f), -0.284496736f),
                          0.254829592f);
            float er = 1.f - poly * __expf(-z * z);
            er = (z < 0.f) ? -er : er;
            float ge = 0.5f * v * (1.f + er);
            row[128 + icg] = f2bf(ge);
        }
    }
    __syncthreads();

    const int wv = tid >> 6;
    const int l  = tid & 63;
    const int la = l & 31, klo = l >> 5;
    const int p0row = la >> 4, p0col = la & 15;   // tile0: rows 0-1; tile1: +2

    f32x16 accA, accB;
#pragma unroll
    for (int i = 0; i < 16; ++i) { accA[i] = 0.f; accB[i] = 0.f; }
    const short8* w8 = (const short8*)w2;

#pragma unroll
    for (int t2 = 0; t2 < 2; ++t2) {
        const int tap = wv * 2 + t2;
        const int kh = tap / 3, kw = tap - kh * 3;
        const ushort* fb0 = &Fs[((p0row + kh) * 18 + (p0col + kw)) * 152 + klo * 8];
        const ushort* fb1 = fb0 + 2 * 18 * 152;
        const short8* ap = w8 + tap * 576 + l;
#pragma unroll
        for (int ks = 0; ks < 9; ++ks) {
            short8 a   = ap[ks * 64];
            short8 bf0 = *(const short8*)(fb0 + ks * 16);
            short8 bf1 = *(const short8*)(fb1 + ks * 16);
            accA = __builtin_amdgcn_mfma_f32_32x32x16_bf16(a, bf0, accA, 0, 0, 0);
            accB = __builtin_amdgcn_mfma_f32_32x32x16_bf16(a, bf1, accB, 0, 0, 0);
        }
    }
    if (wv == 3) {                         // 9th tap (kh=2,kw=2)
        const ushort* fb0 = &Fs[((p0row + 2) * 18 + (p0col + 2)) * 152 + klo * 8];
        const ushort* fb1 = fb0 + 2 * 18 * 152;
        const short8* ap = w8 + 8 * 576 + l;
#pragma unroll
        for (int ks = 0; ks < 9; ++ks) {
            short8 a   = ap[ks * 64];
            short8 bf0 = *(const short8*)(fb0 + ks * 16);
            short8 bf1 = *(const short8*)(fb1 + ks * 16);
            accA = __builtin_amdgcn_mfma_f32_32x32x16_bf16(a, bf0, accA, 0, 0, 0);
            accB = __builtin_amdgcn_mfma_f32_32x32x16_bf16(a, bf1, accB, 0, 0, 0);
        }
    }

    // ---- combine: 6 slots [slot][lane] stride 20 f32 (30,720 B in Fs) ----
    __syncthreads();                      // all feature reads done
    float* comb = (float*)Fs;
    if (wv != 0) {                        // tile0 partials: waves 1,2,3 -> 0,1,2
        float* cp = comb + ((wv - 1) * 64 + l) * 20;
        *(f32x4*)(cp + 0)  = f32x4{accA[0], accA[1], accA[2], accA[3]};
        *(f32x4*)(cp + 4)  = f32x4{accA[4], accA[5], accA[6], accA[7]};
        *(f32x4*)(cp + 8)  = f32x4{accA[8], accA[9], accA[10], accA[11]};
        *(f32x4*)(cp + 12) = f32x4{accA[12], accA[13], accA[14], accA[15]};
    }
    if (wv != 1) {                        // tile1 partials: waves 0,2,3 -> 3,4,5
        int slot = (wv == 0) ? 3 : (2 + wv);
        float* cp = comb + (slot * 64 + l) * 20;
        *(f32x4*)(cp + 0)  = f32x4{accB[0], accB[1], accB[2], accB[3]};
        *(f32x4*)(cp + 4)  = f32x4{accB[4], accB[5], accB[6], accB[7]};
        *(f32x4*)(cp + 8)  = f32x4{accB[8], accB[9], accB[10], accB[11]};
        *(f32x4*)(cp + 12) = f32x4{accB[12], accB[13], accB[14], accB[15]};
    }
    __syncthreads();
    if (wv < 2) {
        f32x16 sum = (wv == 0) ? accA : accB;
        const int sbase = (wv == 0) ? 0 : 3;
#pragma unroll
        for (int s = 0; s < 3; ++s) {
            const float* cp = comb + ((sbase + s) * 64 + l) * 20;
            f32x4 c0 = *(const f32x4*)(cp + 0);
            f32x4 c1 = *(const f32x4*)(cp + 4);
            f32x4 c2 = *(const f32x4*)(cp + 8);
            f32x4 c3 = *(const f32x4*)(cp + 12);
#pragma unroll
            for (int r = 0; r < 4; ++r) {
                sum[r]      += c0[r];
                sum[r + 4]  += c1[r];
                sum[r + 8]  += c2[r];
                sum[r + 12] += c3[r];
            }
        }
        // D: col(pixel) = lane&31, row(oc) = (r&3) + 8*(r>>2) + 4*klo
        const int pix = wv * 32 + la;
        const int prow = pix >> 4, pcol = pix & 15;
        ushort* yb = yraw + (((size_t)b * 128 + g * 32) * 64 + h0 + prow) * 64
                          + w0 + pcol;
#pragma unroll
        for (int r = 0; r < 16; ++r) {
            int oc = (r & 3) + 8 * (r >> 2) + 4 * klo;
            yb[(size_t)oc * 4096] = f2bf(sum[r]);
        }
    }
}

// ---------------------------------------------------------------------------
// Instance-norm + PReLU from bf16 raw y: one block per (b,c); each thread owns
// 16 CONTIGUOUS values; 2 b128 loads + 4 float4 stores per thread.
// ---------------------------------------------------------------------------
__global__ __launch_bounds__(256) void instnorm(const ushort* __restrict__ yraw,
                                                float* __restrict__ y,
                                                const float* __restrict__ prelu) {
    const int blk = blockIdx.x;  // b*128 + c
    const int tid = threadIdx.x;
    const short8* rp = (const short8*)(yraw + (size_t)blk * 4096);
    short8 a = rp[tid * 2], c = rp[tid * 2 + 1];
    float v[16];
#pragma unroll
    for (int j = 0; j < 8; ++j) {
        v[j]     = __uint_as_float(((u32)(ushort)a[j]) << 16);
        v[8 + j] = __uint_as_float(((u32)(ushort)c[j]) << 16);
    }
    float s = 0.f, s2 = 0.f;
#pragma unroll
    for (int j = 0; j < 16; ++j) { s += v[j]; s2 += v[j] * v[j]; }
#pragma unroll
    for (int off = 32; off > 0; off >>= 1) {
        s  += __shfl_down(s, off);
        s2 += __shfl_down(s2, off);
    }
    __shared__ float red[8];
    int wave = tid >> 6;
    if ((tid & 63) == 0) { red[wave] = s; red[4 + wave] = s2; }
    __syncthreads();
    float S  = red[0] + red[1] + red[2] + red[3];
    float S2 = red[4] + red[5] + red[6] + red[7];
    float mean = S * (1.0f / 4096.0f);
    float var  = S2 * (1.0f / 4096.0f) - mean * mean;
    float rstd = rsqrtf(var + 1e-5f);
    float slope = prelu[(blk >> 5) & 3];
    float4* op = (float4*)(y + (size_t)blk * 4096) + tid * 4;
#pragma unroll
    for (int k = 0; k < 4; ++k) {
        float4 o;
        float t;
        t = (v[k * 4 + 0] - mean) * rstd; o.x = t >= 0.f ? t : slope * t;
        t = (v[k * 4 + 1] - mean) * rstd; o.y = t >= 0.f ? t : slope * t;
        t = (v[k * 4 + 2] - mean) * rstd; o.z = t >= 0.f ? t : slope * t;
        t = (v[k * 4 + 3] - mean) * rstd; o.w = t >= 0.f ? t : slope * t;
        op[k] = o;
    }
}

extern "C" void kernel_launch(void* const* d_in, const int* in_sizes, int n_in,
                              void* d_out, int out_size, void* d_ws, size_t ws_size,
                              hipStream_t stream) {
    const float* x     = (const float*)d_in[0];
    const float* lw    = (const float*)d_in[1];
    const float* prelu = (const float*)d_in[2];
    float*  out  = (float*)d_out;
    ushort* w2   = (ushort*)d_ws;                       // 82,944 B
    ushort* yraw = (ushort*)((char*)d_ws + 92160);      // 8 MB bf16 raw y

    wtrans<<<21, 256, 0, stream>>>(lw, w2);
    dim3 grid(64, 8, 4);
    kanconv<<<grid, 256, 0, stream>>>(x, w2, yraw);
    instnorm<<<1024, 256, 0, stream>>>(yraw, out, prelu);
}